// Round 5
// baseline (172.782 us; speedup 1.0000x reference)
//
#include <hip/hip_runtime.h>

// N-gram embedding mean on gfx950, deduplicated.
// word_idx has ~37% duplicate positions (32768 draws over V=32000). We elect
// one "owner" position per distinct word via atomicCAS, gather/accumulate only
// for owners (cuts the 210MB random-gather stream by ~37%), then scatter-copy
// owners' 512B output rows to duplicate positions. The gather kernel keeps
// R4's structure: scalar (SGPR) row ids, all loads hoisted above accumulates,
// wave-uniform branches only.
#define VOCAB 32000
#define NUM_WORDS 32768   // B*S = 16*2048
#define KMAX 24

__global__ __launch_bounds__(256) void init_slots(int* __restrict__ slot) {
    const int i = blockIdx.x * blockDim.x + threadIdx.x;
    if (i < VOCAB) slot[i] = -1;
}

__global__ __launch_bounds__(256) void claim_owners(
    const int* __restrict__ word_idx, int* __restrict__ slot) {
    const int p = blockIdx.x * blockDim.x + threadIdx.x;
    if (p < NUM_WORDS) atomicCAS(&slot[word_idx[p]], -1, p);
}

__global__ __launch_bounds__(256) void ngram_emb_owner_kernel(
    const int* __restrict__ word_idx,      // [B*S]
    const int* __restrict__ ngram_ids,     // [V, K]
    const int* __restrict__ ngram_counts,  // [V]
    const float* __restrict__ emb_table,   // [NG, E]
    const int* __restrict__ slot,          // [V] owner position per word
    float* __restrict__ out)               // [B*S, E]
{
    const int gtid = blockIdx.x * blockDim.x + threadIdx.x;
    const int p    = gtid >> 6;            // one wave per position
    const int lane = threadIdx.x & 63;     // float2 chunk within the 512B row

    const int w = __builtin_amdgcn_readfirstlane(word_idx[p]);   // uniform
    if (slot[w] != p) return;              // wave-uniform: only owners compute

    const int cnt = ngram_counts[w];       // uniform scalar load
    const int* ids = ngram_ids + w * KMAX;

    int rr[KMAX];
#pragma unroll
    for (int k = 0; k < KMAX; ++k)
        rr[k] = __builtin_amdgcn_readfirstlane(ids[k]);

    const float2* tbl = (const float2*)emb_table;   // row stride = 64 float2

    // phase 1: issue every load (uniform group skips, no accumulates)
    float2 v[KMAX];
#pragma unroll
    for (int j = 0; j < 8; ++j)
        v[j] = tbl[(long)rr[j] * 64 + lane];
    if (cnt > 8) {
#pragma unroll
        for (int j = 8; j < 16; ++j)
            v[j] = tbl[(long)rr[j] * 64 + lane];
    }
    if (cnt > 16) {
#pragma unroll
        for (int j = 16; j < 24; ++j)
            v[j] = tbl[(long)rr[j] * 64 + lane];
    }

    // phase 2: masked accumulate (masks are wave-uniform scalars)
    float ax = 0.f, ay = 0.f;
#pragma unroll
    for (int j = 0; j < 8; ++j) {
        const float m = rr[j] ? 1.f : 0.f;
        ax = fmaf(m, v[j].x, ax);
        ay = fmaf(m, v[j].y, ay);
    }
    if (cnt > 8) {
#pragma unroll
        for (int j = 8; j < 16; ++j) {
            const float m = rr[j] ? 1.f : 0.f;
            ax = fmaf(m, v[j].x, ax);
            ay = fmaf(m, v[j].y, ay);
        }
    }
    if (cnt > 16) {
#pragma unroll
        for (int j = 16; j < 24; ++j) {
            const float m = rr[j] ? 1.f : 0.f;
            ax = fmaf(m, v[j].x, ax);
            ay = fmaf(m, v[j].y, ay);
        }
    }

    const float inv = 1.0f / (float)cnt;
    float2 o; o.x = ax * inv; o.y = ay * inv;
    ((float2*)out)[(long)p * 64 + lane] = o;       // 64 lanes x 8B = 512B row
}

__global__ __launch_bounds__(256) void scatter_dups(
    const int* __restrict__ word_idx,
    const int* __restrict__ slot,
    float* __restrict__ out)
{
    const int gtid = blockIdx.x * blockDim.x + threadIdx.x;
    const int p    = gtid >> 6;
    const int lane = threadIdx.x & 63;

    const int w     = __builtin_amdgcn_readfirstlane(word_idx[p]);
    const int owner = slot[w];             // uniform
    if (owner == p) return;                // owners already written

    float2* o2 = (float2*)out;
    o2[(long)p * 64 + lane] = o2[(long)owner * 64 + lane];
}

extern "C" void kernel_launch(void* const* d_in, const int* in_sizes, int n_in,
                              void* d_out, int out_size, void* d_ws, size_t ws_size,
                              hipStream_t stream) {
    const int*   word_idx     = (const int*)d_in[0];
    const int*   ngram_ids    = (const int*)d_in[1];
    const int*   ngram_counts = (const int*)d_in[2];
    const float* emb_table    = (const float*)d_in[3];
    float*       out          = (float*)d_out;
    int*         slot         = (int*)d_ws;          // VOCAB ints of scratch

    init_slots<<<(VOCAB + 255) / 256, 256, 0, stream>>>(slot);
    claim_owners<<<(NUM_WORDS + 255) / 256, 256, 0, stream>>>(word_idx, slot);

    const int threads = 256;
    const int blocks  = (NUM_WORDS * 64) / threads;  // 8192 (wave per position)
    ngram_emb_owner_kernel<<<blocks, threads, 0, stream>>>(
        word_idx, ngram_ids, ngram_counts, emb_table, slot, out);
    scatter_dups<<<blocks, threads, 0, stream>>>(word_idx, slot, out);
}